// Round 2
// baseline (336.565 us; speedup 1.0000x reference)
//
#include <hip/hip_runtime.h>
#include <hip/hip_cooperative_groups.h>

namespace cg = cooperative_groups;

#define FDIM 1000
#define BDIM 2049
#define NTH  256
#define BT   16
#define NBT  129          // ceil(BDIM/BT)

// ---- fused (cooperative) geometry: only 2 blocks/CU co-residency needed ----
#define CFS   3           // f splits
#define CFT   336         // f per block (16*21), guarded by f < FDIM
#define CNII  21          // per-thread point slots (fully unrolled, static idx)
#define CGRID (NBT * CFS) // 387 blocks <= 512 (2/CU)

// ---- fallback geometry: the proven 3-kernel pipeline ----
#define FFS   8
#define FFT   125
#define FGRID (NBT * FFS)

// out layout (floats): y_out (F,B,C,2,S) | v (F,B,S) | R (B,C,C,2,S)
#define V_OFF 32784000ull
#define R_OFF 40980000ull

// ws layout (floats): part1[B][8][20] | part2[B][8][20] (CFS=3 fits inside stride-8 region? no —
// fused uses its own stride CFS within the part1/part2 regions; regions sized for 8)
#define P2_OFF ((size_t)BDIM * 8 * 20)

#define EPSF 1.1920928955078125e-07f
#define REGC 3.4526698300124393e-04f

// ===================== fused cooperative kernel =====================
//   P1: stream y -> v1 (registers), partial R1 -> part1      | grid.sync
//   P2: reduce R1, filter (v1,x) -> v2 (regs), partial R2    | grid.sync
//   P3: reduce R2, write Rout; filter (v2,x) -> y_out, v
__global__ __launch_bounds__(NTH, 2) void k_fused(
    const float* __restrict__ y, const float* __restrict__ x,
    float* __restrict__ yout, float* __restrict__ vout, float* __restrict__ Rout,
    float* __restrict__ part1, float* __restrict__ part2,
    const int* __restrict__ itp)
{
    cg::grid_group gg = cg::this_grid();
    const int btile = blockIdx.x / CFS;
    const int fs    = blockIdx.x % CFS;
    const int tid   = threadIdx.x;
    const int bs    = tid & 15;
    const int fi    = tid >> 4;          // 0..15
    const int wid   = tid >> 6;
    const int b     = btile * BT + bs;
    const bool vb   = (b < BDIM);
    const int iters = itp[0];
    const int f0    = fs * CFT;

    __shared__ float red[4][16][20];
    __shared__ float rsumS[16][20];
    __shared__ float rnormS[16][16];

    // ---------------- Phase 1 ----------------
    float vst[CNII][4];
    float acc[20];
    #pragma unroll
    for (int j = 0; j < 20; ++j) acc[j] = 0.f;

    #pragma unroll
    for (int ii = 0; ii < CNII; ++ii) {
        const int f = f0 + ii * 16 + fi;
        #pragma unroll
        for (int s = 0; s < 4; ++s) vst[ii][s] = 0.f;
        if ((f < FDIM) && vb) {
            const size_t e = (size_t)f * BDIM + b;
            const float4* yp = reinterpret_cast<const float4*>(y) + e * 4;
            const float4 a0 = yp[0], a1 = yp[1], a2 = yp[2], a3 = yp[3];
            const float y0r[4] = {a0.x,a0.y,a0.z,a0.w};
            const float y0i[4] = {a1.x,a1.y,a1.z,a1.w};
            const float y1r[4] = {a2.x,a2.y,a2.z,a2.w};
            const float y1i[4] = {a3.x,a3.y,a3.z,a3.w};
            #pragma unroll
            for (int s = 0; s < 4; ++s) {
                const float p0 = y0r[s]*y0r[s] + y0i[s]*y0i[s];
                const float p1 = y1r[s]*y1r[s] + y1i[s]*y1i[s];
                vst[ii][s] = 0.5f * (p0 + p1);
                acc[s]    += p0;
                acc[4+s]  += p1;
                acc[8+s]  += y0r[s]*y1r[s] + y0i[s]*y1i[s];
                acc[12+s] += y0i[s]*y1r[s] - y0r[s]*y1i[s];
                acc[16+s] += vst[ii][s];
            }
        }
    }
    #pragma unroll
    for (int j = 0; j < 20; ++j) {
        float t = acc[j];
        t += __shfl_xor(t, 16);
        t += __shfl_xor(t, 32);
        acc[j] = t;
    }
    if ((tid & 63) < 16) {
        #pragma unroll
        for (int j = 0; j < 20; ++j) red[wid][bs][j] = acc[j];
    }
    __syncthreads();
    for (int idx = tid; idx < 320; idx += NTH) {
        const int bss = idx & 15, j = idx >> 4;
        const int bb = btile * BT + bss;
        if (bb < BDIM)
            part1[((size_t)bb * CFS + fs) * 20 + j] =
                red[0][bss][j] + red[1][bss][j] + red[2][bss][j] + red[3][bss][j];
    }

    gg.sync();

    // ---------------- Phase 2 ----------------
    for (int idx = tid; idx < 320; idx += NTH) {
        const int bss = idx & 15, j = idx >> 4;
        const int bb = btile * BT + bss;
        float s = 0.f;
        if (bb < BDIM) {
            #pragma unroll
            for (int q = 0; q < CFS; ++q) s += part1[((size_t)bb * CFS + q) * 20 + j];
        }
        rsumS[bss][j] = s;
    }
    __syncthreads();
    {
        const int bss = tid & 15, j = tid >> 4;   // 256 threads == 16x16
        rnormS[bss][j] = rsumS[bss][j] / (EPSF + rsumS[bss][16 + (j & 3)]);
    }
    __syncthreads();

    if (iters >= 2) {
        float rn00[4], rn11[4], rn01r[4], rn01i[4];
        #pragma unroll
        for (int s = 0; s < 4; ++s) {
            rn00[s]=rnormS[bs][s]; rn11[s]=rnormS[bs][4+s];
            rn01r[s]=rnormS[bs][8+s]; rn01i[s]=rnormS[bs][12+s];
        }
        #pragma unroll
        for (int j = 0; j < 20; ++j) acc[j] = 0.f;

        #pragma unroll
        for (int ii = 0; ii < CNII; ++ii) {
            const int f = f0 + ii * 16 + fi;
            if ((f < FDIM) && vb) {
                const size_t e = (size_t)f * BDIM + b;
                const float4 xv = reinterpret_cast<const float4*>(x)[e];
                float c00 = REGC, c11 = REGC, c01r = 0.f, c01i = 0.f;
                #pragma unroll
                for (int s = 0; s < 4; ++s) {
                    c00  += vst[ii][s]*rn00[s];
                    c11  += vst[ii][s]*rn11[s];
                    c01r += vst[ii][s]*rn01r[s];
                    c01i += vst[ii][s]*rn01i[s];
                }
                const float det  = c00*c11 - (c01r*c01r + c01i*c01i);
                const float invd = det / (det*det);
                const float i00 = invd*c11, i11 = invd*c00;
                const float i01r = -invd*c01r, i01i = -invd*c01i;
                const float xr0 = xv.x, xi0 = xv.y, xr1 = xv.z, xi1 = xv.w;
                const float w0r = i00*xr0 + (i01r*xr1 - i01i*xi1);
                const float w0i = i00*xi0 + (i01r*xi1 + i01i*xr1);
                const float w1r = (i01r*xr0 + i01i*xi0) + i11*xr1;
                const float w1i = (i01r*xi0 - i01i*xr0) + i11*xi1;
                #pragma unroll
                for (int s = 0; s < 4; ++s) {
                    const float vs = vst[ii][s];
                    const float y0r = vs*(rn00[s]*w0r + (rn01r[s]*w1r - rn01i[s]*w1i));
                    const float y0i = vs*(rn00[s]*w0i + (rn01r[s]*w1i + rn01i[s]*w1r));
                    const float y1r = vs*((rn01r[s]*w0r + rn01i[s]*w0i) + rn11[s]*w1r);
                    const float y1i = vs*((rn01r[s]*w0i - rn01i[s]*w0r) + rn11[s]*w1i);
                    const float p0 = y0r*y0r + y0i*y0i;
                    const float p1 = y1r*y1r + y1i*y1i;
                    const float v2 = 0.5f*(p0 + p1);
                    vst[ii][s] = v2;
                    acc[s]    += p0;
                    acc[4+s]  += p1;
                    acc[8+s]  += y0r*y1r + y0i*y1i;
                    acc[12+s] += y0i*y1r - y0r*y1i;
                    acc[16+s] += v2;
                }
            }
        }
        #pragma unroll
        for (int j = 0; j < 20; ++j) {
            float t = acc[j];
            t += __shfl_xor(t, 16);
            t += __shfl_xor(t, 32);
            acc[j] = t;
        }
        if ((tid & 63) < 16) {
            #pragma unroll
            for (int j = 0; j < 20; ++j) red[wid][bs][j] = acc[j];
        }
        __syncthreads();
        for (int idx = tid; idx < 320; idx += NTH) {
            const int bss = idx & 15, j = idx >> 4;
            const int bb = btile * BT + bss;
            if (bb < BDIM)
                part2[((size_t)bb * CFS + fs) * 20 + j] =
                    red[0][bss][j] + red[1][bss][j] + red[2][bss][j] + red[3][bss][j];
        }
    } else {
        for (int idx = tid; idx < 320; idx += NTH) {
            const int bss = idx & 15, j = idx >> 4;
            const int bb = btile * BT + bss;
            if (bb < BDIM)
                part2[((size_t)bb * CFS + fs) * 20 + j] = (fs == 0) ? rsumS[bss][j] : 0.f;
        }
    }

    gg.sync();

    // ---------------- Phase 3 ----------------
    for (int idx = tid; idx < 320; idx += NTH) {
        const int bss = idx & 15, j = idx >> 4;
        const int bb = btile * BT + bss;
        float s = 0.f;
        if (bb < BDIM) {
            #pragma unroll
            for (int q = 0; q < CFS; ++q) s += part2[((size_t)bb * CFS + q) * 20 + j];
        }
        rsumS[bss][j] = s;
    }
    __syncthreads();
    {
        const int bss = tid & 15, j = tid >> 4;
        rnormS[bss][j] = rsumS[bss][j] / (EPSF + rsumS[bss][16 + (j & 3)]);
    }
    __syncthreads();

    if (fs == 0) {   // R_out
        for (int idx = tid; idx < 512; idx += NTH) {
            const int bss = idx >> 5, r = idx & 31;
            const int bb = btile * BT + bss;
            if (bb < BDIM) {
                const int c = (r>>4)&1, d = (r>>3)&1, ri = (r>>2)&1, s = r&3;
                const bool raw = (iters == 0);
                float val;
                if (c == d) {
                    val = ri ? 0.f : (raw ? rsumS[bss][(c?4:0)+s] : rnormS[bss][(c?4:0)+s]);
                } else {
                    const float re = raw ? rsumS[bss][8+s]  : rnormS[bss][8+s];
                    const float im = raw ? rsumS[bss][12+s] : rnormS[bss][12+s];
                    val = ri ? (c == 0 ? im : -im) : re;
                }
                Rout[(size_t)bb * 32 + r] = val;
            }
        }
    }

    if (iters == 0) {   // y_out = y, v = v1
        #pragma unroll
        for (int ii = 0; ii < CNII; ++ii) {
            const int f = f0 + ii * 16 + fi;
            if ((f < FDIM) && vb) {
                const size_t e = (size_t)f * BDIM + b;
                const float4* yp = reinterpret_cast<const float4*>(y) + e * 4;
                float4* op = reinterpret_cast<float4*>(yout) + e * 4;
                op[0] = yp[0]; op[1] = yp[1]; op[2] = yp[2]; op[3] = yp[3];
                reinterpret_cast<float4*>(vout)[e] =
                    make_float4(vst[ii][0], vst[ii][1], vst[ii][2], vst[ii][3]);
            }
        }
        return;
    }

    float rn00[4], rn11[4], rn01r[4], rn01i[4];
    #pragma unroll
    for (int s = 0; s < 4; ++s) {
        rn00[s]=rnormS[bs][s]; rn11[s]=rnormS[bs][4+s];
        rn01r[s]=rnormS[bs][8+s]; rn01i[s]=rnormS[bs][12+s];
    }

    #pragma unroll
    for (int ii = 0; ii < CNII; ++ii) {
        const int f = f0 + ii * 16 + fi;
        if ((f < FDIM) && vb) {
            const size_t e = (size_t)f * BDIM + b;
            const float4 xv = reinterpret_cast<const float4*>(x)[e];
            float c00 = REGC, c11 = REGC, c01r = 0.f, c01i = 0.f;
            #pragma unroll
            for (int s = 0; s < 4; ++s) {
                c00  += vst[ii][s]*rn00[s];
                c11  += vst[ii][s]*rn11[s];
                c01r += vst[ii][s]*rn01r[s];
                c01i += vst[ii][s]*rn01i[s];
            }
            const float det  = c00*c11 - (c01r*c01r + c01i*c01i);
            const float invd = det / (det*det);
            const float i00 = invd*c11, i11 = invd*c00;
            const float i01r = -invd*c01r, i01i = -invd*c01i;
            const float xr0 = xv.x, xi0 = xv.y, xr1 = xv.z, xi1 = xv.w;
            const float w0r = i00*xr0 + (i01r*xr1 - i01i*xi1);
            const float w0i = i00*xi0 + (i01r*xi1 + i01i*xr1);
            const float w1r = (i01r*xr0 + i01i*xi0) + i11*xr1;
            const float w1i = (i01r*xi0 - i01i*xr0) + i11*xi1;
            float o0r[4], o0i[4], o1r[4], o1i[4];
            #pragma unroll
            for (int s = 0; s < 4; ++s) {
                const float vs = vst[ii][s];
                o0r[s] = vs*(rn00[s]*w0r + (rn01r[s]*w1r - rn01i[s]*w1i));
                o0i[s] = vs*(rn00[s]*w0i + (rn01r[s]*w1i + rn01i[s]*w1r));
                o1r[s] = vs*((rn01r[s]*w0r + rn01i[s]*w0i) + rn11[s]*w1r);
                o1i[s] = vs*((rn01r[s]*w0i - rn01i[s]*w0r) + rn11[s]*w1i);
            }
            float4* op = reinterpret_cast<float4*>(yout) + e * 4;
            op[0] = make_float4(o0r[0], o0r[1], o0r[2], o0r[3]);
            op[1] = make_float4(o0i[0], o0i[1], o0i[2], o0i[3]);
            op[2] = make_float4(o1r[0], o1r[1], o1r[2], o1r[3]);
            op[3] = make_float4(o1i[0], o1i[1], o1i[2], o1i[3]);
            reinterpret_cast<float4*>(vout)[e] =
                make_float4(vst[ii][0], vst[ii][1], vst[ii][2], vst[ii][3]);
        }
    }
}

// ===================== fallback: proven 3-kernel pipeline =====================
__global__ __launch_bounds__(NTH) void k1_power(
    const float* __restrict__ y, float* __restrict__ v, float* __restrict__ part1)
{
    const int btile = blockIdx.x / FFS;
    const int fs    = blockIdx.x % FFS;
    const int tid   = threadIdx.x;
    const int bs    = tid & 15;
    const int fi    = tid >> 4;
    const int wid   = tid >> 6;
    const int b     = btile * BT + bs;
    const bool vb   = (b < BDIM);

    float acc[20];
    #pragma unroll
    for (int j = 0; j < 20; ++j) acc[j] = 0.f;

    const int f0 = fs * FFT;
    #pragma unroll
    for (int ii = 0; ii < 8; ++ii) {
        const int fo = ii * 16 + fi;
        if (fo < FFT && vb) {
            const int f = f0 + fo;
            const size_t e = (size_t)f * BDIM + b;
            const float4* yp = reinterpret_cast<const float4*>(y) + e * 4;
            float4 a0 = yp[0], a1 = yp[1], a2 = yp[2], a3 = yp[3];
            float y0r[4] = {a0.x,a0.y,a0.z,a0.w};
            float y0i[4] = {a1.x,a1.y,a1.z,a1.w};
            float y1r[4] = {a2.x,a2.y,a2.z,a2.w};
            float y1i[4] = {a3.x,a3.y,a3.z,a3.w};
            float vv[4];
            #pragma unroll
            for (int s = 0; s < 4; ++s) {
                const float p0 = y0r[s]*y0r[s] + y0i[s]*y0i[s];
                const float p1 = y1r[s]*y1r[s] + y1i[s]*y1i[s];
                vv[s] = 0.5f * (p0 + p1);
                acc[s]    += p0;
                acc[4+s]  += p1;
                acc[8+s]  += y0r[s]*y1r[s] + y0i[s]*y1i[s];
                acc[12+s] += y0i[s]*y1r[s] - y0r[s]*y1i[s];
                acc[16+s] += vv[s];
            }
            reinterpret_cast<float4*>(v)[e] = make_float4(vv[0], vv[1], vv[2], vv[3]);
        }
    }
    #pragma unroll
    for (int j = 0; j < 20; ++j) {
        float t = acc[j];
        t += __shfl_xor(t, 16);
        t += __shfl_xor(t, 32);
        acc[j] = t;
    }
    __shared__ float red[4][16][20];
    if ((tid & 63) < 16) {
        #pragma unroll
        for (int j = 0; j < 20; ++j) red[wid][bs][j] = acc[j];
    }
    __syncthreads();
    for (int idx = tid; idx < 320; idx += NTH) {
        const int bss = idx & 15, j = idx >> 4;
        const int bb = btile * BT + bss;
        if (bb < BDIM)
            part1[((size_t)bb * FFS + fs) * 20 + j] =
                red[0][bss][j] + red[1][bss][j] + red[2][bss][j] + red[3][bss][j];
    }
}

__global__ __launch_bounds__(NTH) void k3_em(
    const float* __restrict__ x, float* __restrict__ v,
    const float* __restrict__ part1, float* __restrict__ part2,
    const int* __restrict__ itp)
{
    const int btile = blockIdx.x / FFS;
    const int fs    = blockIdx.x % FFS;
    const int tid   = threadIdx.x;
    const int bs    = tid & 15;
    const int fi    = tid >> 4;
    const int wid   = tid >> 6;
    const int b     = btile * BT + bs;
    const bool vb   = (b < BDIM);
    const int iters = itp[0];

    __shared__ float rsumS[16][20];
    __shared__ float rnormS[16][16];
    for (int idx = tid; idx < 320; idx += NTH) {
        const int bss = idx & 15, j = idx >> 4;
        const int bb = btile * BT + bss;
        float s = 0.f;
        if (bb < BDIM) {
            #pragma unroll
            for (int q = 0; q < FFS; ++q) s += part1[((size_t)bb * FFS + q) * 20 + j];
        }
        rsumS[bss][j] = s;
    }
    __syncthreads();
    {
        const int bss = tid & 15, j = tid >> 4;
        rnormS[bss][j] = rsumS[bss][j] / (EPSF + rsumS[bss][16 + (j & 3)]);
    }
    __syncthreads();

    if (iters <= 1) {
        for (int idx = tid; idx < 320; idx += NTH) {
            const int bss = idx & 15, j = idx >> 4;
            const int bb = btile * BT + bss;
            if (bb < BDIM)
                part2[((size_t)bb * FFS + fs) * 20 + j] = (fs == 0) ? rsumS[bss][j] : 0.f;
        }
        return;
    }

    float rn00[4], rn11[4], rn01r[4], rn01i[4];
    #pragma unroll
    for (int s = 0; s < 4; ++s) {
        rn00[s]=rnormS[bs][s]; rn11[s]=rnormS[bs][4+s];
        rn01r[s]=rnormS[bs][8+s]; rn01i[s]=rnormS[bs][12+s];
    }

    float acc[20];
    #pragma unroll
    for (int j = 0; j < 20; ++j) acc[j] = 0.f;

    const int f0 = fs * FFT;
    #pragma unroll
    for (int ii = 0; ii < 8; ++ii) {
        const int fo = ii * 16 + fi;
        if (fo < FFT && vb) {
            const int f = f0 + fo;
            const size_t e = (size_t)f * BDIM + b;
            float4 vv4 = reinterpret_cast<const float4*>(v)[e];
            float4 xv  = reinterpret_cast<const float4*>(x)[e];
            float v1[4] = {vv4.x, vv4.y, vv4.z, vv4.w};
            float c00 = REGC, c11 = REGC, c01r = 0.f, c01i = 0.f;
            #pragma unroll
            for (int s = 0; s < 4; ++s) {
                c00  += v1[s]*rn00[s];
                c11  += v1[s]*rn11[s];
                c01r += v1[s]*rn01r[s];
                c01i += v1[s]*rn01i[s];
            }
            const float det  = c00*c11 - (c01r*c01r + c01i*c01i);
            const float invd = det / (det*det);
            const float i00 = invd*c11, i11 = invd*c00;
            const float i01r = -invd*c01r, i01i = -invd*c01i;
            const float xr0 = xv.x, xi0 = xv.y, xr1 = xv.z, xi1 = xv.w;
            const float w0r = i00*xr0 + (i01r*xr1 - i01i*xi1);
            const float w0i = i00*xi0 + (i01r*xi1 + i01i*xr1);
            const float w1r = (i01r*xr0 + i01i*xi0) + i11*xr1;
            const float w1i = (i01r*xi0 - i01i*xr0) + i11*xi1;
            float v2[4];
            #pragma unroll
            for (int s = 0; s < 4; ++s) {
                const float vs = v1[s];
                const float y0r = vs*(rn00[s]*w0r + (rn01r[s]*w1r - rn01i[s]*w1i));
                const float y0i = vs*(rn00[s]*w0i + (rn01r[s]*w1i + rn01i[s]*w1r));
                const float y1r = vs*((rn01r[s]*w0r + rn01i[s]*w0i) + rn11[s]*w1r);
                const float y1i = vs*((rn01r[s]*w0i - rn01i[s]*w0r) + rn11[s]*w1i);
                const float p0 = y0r*y0r + y0i*y0i;
                const float p1 = y1r*y1r + y1i*y1i;
                v2[s] = 0.5f*(p0 + p1);
                acc[s]    += p0;
                acc[4+s]  += p1;
                acc[8+s]  += y0r*y1r + y0i*y1i;
                acc[12+s] += y0i*y1r - y0r*y1i;
                acc[16+s] += v2[s];
            }
            reinterpret_cast<float4*>(v)[e] = make_float4(v2[0], v2[1], v2[2], v2[3]);
        }
    }
    #pragma unroll
    for (int j = 0; j < 20; ++j) {
        float t = acc[j];
        t += __shfl_xor(t, 16);
        t += __shfl_xor(t, 32);
        acc[j] = t;
    }
    __shared__ float red[4][16][20];
    if ((tid & 63) < 16) {
        #pragma unroll
        for (int j = 0; j < 20; ++j) red[wid][bs][j] = acc[j];
    }
    __syncthreads();
    for (int idx = tid; idx < 320; idx += NTH) {
        const int bss = idx & 15, j = idx >> 4;
        const int bb = btile * BT + bss;
        if (bb < BDIM)
            part2[((size_t)bb * FFS + fs) * 20 + j] =
                red[0][bss][j] + red[1][bss][j] + red[2][bss][j] + red[3][bss][j];
    }
}

__global__ __launch_bounds__(NTH) void k5_final(
    const float* __restrict__ y, const float* __restrict__ x, const float* __restrict__ v,
    const float* __restrict__ part2, float* __restrict__ yout, float* __restrict__ Rout,
    const int* __restrict__ itp)
{
    const int btile = blockIdx.x / FFS;
    const int fs    = blockIdx.x % FFS;
    const int tid   = threadIdx.x;
    const int bs    = tid & 15;
    const int fi    = tid >> 4;
    const int b     = btile * BT + bs;
    const bool vb   = (b < BDIM);
    const int iters = itp[0];

    __shared__ float rsumS[16][20];
    __shared__ float rnormS[16][16];
    for (int idx = tid; idx < 320; idx += NTH) {
        const int bss = idx & 15, j = idx >> 4;
        const int bb = btile * BT + bss;
        float s = 0.f;
        if (bb < BDIM) {
            #pragma unroll
            for (int q = 0; q < FFS; ++q) s += part2[((size_t)bb * FFS + q) * 20 + j];
        }
        rsumS[bss][j] = s;
    }
    __syncthreads();
    {
        const int bss = tid & 15, j = tid >> 4;
        rnormS[bss][j] = rsumS[bss][j] / (EPSF + rsumS[bss][16 + (j & 3)]);
    }
    __syncthreads();

    if (fs == 0) {
        for (int idx = tid; idx < 512; idx += NTH) {
            const int bss = idx >> 5, r = idx & 31;
            const int bb = btile * BT + bss;
            if (bb < BDIM) {
                const int c = (r>>4)&1, d = (r>>3)&1, ri = (r>>2)&1, s = r&3;
                const bool raw = (iters == 0);
                float val;
                if (c == d) {
                    val = ri ? 0.f : (raw ? rsumS[bss][(c?4:0)+s] : rnormS[bss][(c?4:0)+s]);
                } else {
                    const float re = raw ? rsumS[bss][8+s]  : rnormS[bss][8+s];
                    const float im = raw ? rsumS[bss][12+s] : rnormS[bss][12+s];
                    val = ri ? (c == 0 ? im : -im) : re;
                }
                Rout[(size_t)bb * 32 + r] = val;
            }
        }
    }

    const int f0 = fs * FFT;
    if (iters == 0) {
        #pragma unroll
        for (int ii = 0; ii < 8; ++ii) {
            const int fo = ii * 16 + fi;
            if (fo < FFT && vb) {
                const size_t e = (size_t)(f0 + fo) * BDIM + b;
                const float4* yp = reinterpret_cast<const float4*>(y) + e * 4;
                float4* op = reinterpret_cast<float4*>(yout) + e * 4;
                op[0] = yp[0]; op[1] = yp[1]; op[2] = yp[2]; op[3] = yp[3];
            }
        }
        return;
    }

    float rn00[4], rn11[4], rn01r[4], rn01i[4];
    #pragma unroll
    for (int s = 0; s < 4; ++s) {
        rn00[s]=rnormS[bs][s]; rn11[s]=rnormS[bs][4+s];
        rn01r[s]=rnormS[bs][8+s]; rn01i[s]=rnormS[bs][12+s];
    }

    #pragma unroll
    for (int ii = 0; ii < 8; ++ii) {
        const int fo = ii * 16 + fi;
        if (fo < FFT && vb) {
            const int f = f0 + fo;
            const size_t e = (size_t)f * BDIM + b;
            float4 vv4 = reinterpret_cast<const float4*>(v)[e];
            float4 xv  = reinterpret_cast<const float4*>(x)[e];
            float vcur[4] = {vv4.x, vv4.y, vv4.z, vv4.w};
            float c00 = REGC, c11 = REGC, c01r = 0.f, c01i = 0.f;
            #pragma unroll
            for (int s = 0; s < 4; ++s) {
                c00  += vcur[s]*rn00[s];
                c11  += vcur[s]*rn11[s];
                c01r += vcur[s]*rn01r[s];
                c01i += vcur[s]*rn01i[s];
            }
            const float det  = c00*c11 - (c01r*c01r + c01i*c01i);
            const float invd = det / (det*det);
            const float i00 = invd*c11, i11 = invd*c00;
            const float i01r = -invd*c01r, i01i = -invd*c01i;
            const float xr0 = xv.x, xi0 = xv.y, xr1 = xv.z, xi1 = xv.w;
            const float w0r = i00*xr0 + (i01r*xr1 - i01i*xi1);
            const float w0i = i00*xi0 + (i01r*xi1 + i01i*xr1);
            const float w1r = (i01r*xr0 + i01i*xi0) + i11*xr1;
            const float w1i = (i01r*xi0 - i01i*xr0) + i11*xi1;
            float o0r[4], o0i[4], o1r[4], o1i[4];
            #pragma unroll
            for (int s = 0; s < 4; ++s) {
                const float vs = vcur[s];
                o0r[s] = vs*(rn00[s]*w0r + (rn01r[s]*w1r - rn01i[s]*w1i));
                o0i[s] = vs*(rn00[s]*w0i + (rn01r[s]*w1i + rn01i[s]*w1r));
                o1r[s] = vs*((rn01r[s]*w0r + rn01i[s]*w0i) + rn11[s]*w1r);
                o1i[s] = vs*((rn01r[s]*w0i - rn01i[s]*w0r) + rn11[s]*w1i);
            }
            float4* op = reinterpret_cast<float4*>(yout) + e * 4;
            op[0] = make_float4(o0r[0], o0r[1], o0r[2], o0r[3]);
            op[1] = make_float4(o0i[0], o0i[1], o0i[2], o0i[3]);
            op[2] = make_float4(o1r[0], o1r[1], o1r[2], o1r[3]);
            op[3] = make_float4(o1i[0], o1i[1], o1i[2], o1i[3]);
        }
    }
}

extern "C" void kernel_launch(void* const* d_in, const int* in_sizes, int n_in,
                              void* d_out, int out_size, void* d_ws, size_t ws_size,
                              hipStream_t stream) {
    const float* y   = (const float*)d_in[0];
    const float* x   = (const float*)d_in[1];
    const int*   itp = (const int*)d_in[2];
    float* out   = (float*)d_out;
    float* vreg  = out + V_OFF;
    float* Rreg  = out + R_OFF;
    float* part1 = (float*)d_ws;
    float* part2 = part1 + P2_OFF;

    // ---- capacity pre-check (host-only queries; graph-capture-safe) ----
    bool use_coop = false;
    int dev = 0, coop = 0, ncu = 0, maxb = 0;
    if (hipGetDevice(&dev) == hipSuccess &&
        hipDeviceGetAttribute(&coop, hipDeviceAttributeCooperativeLaunch, dev) == hipSuccess &&
        coop != 0 &&
        hipDeviceGetAttribute(&ncu, hipDeviceAttributeMultiprocessorCount, dev) == hipSuccess &&
        hipOccupancyMaxActiveBlocksPerMultiprocessor(&maxb, (const void*)k_fused, NTH, 0) == hipSuccess &&
        (long long)maxb * (long long)ncu >= (long long)CGRID)
        use_coop = true;

    if (use_coop) {
        void* args[] = {(void*)&y, (void*)&x, (void*)&out, (void*)&vreg, (void*)&Rreg,
                        (void*)&part1, (void*)&part2, (void*)&itp};
        if (hipLaunchCooperativeKernel((void*)k_fused, dim3(CGRID), dim3(NTH),
                                       args, 0, stream) != hipSuccess)
            use_coop = false;
    }
    if (!use_coop) {
        k1_power<<<FGRID, NTH, 0, stream>>>(y, vreg, part1);
        k3_em   <<<FGRID, NTH, 0, stream>>>(x, vreg, part1, part2, itp);
        k5_final<<<FGRID, NTH, 0, stream>>>(y, x, vreg, part2, out, Rreg, itp);
    }
}

// Round 3
// 335.816 us; speedup vs baseline: 1.0022x; 1.0022x over previous
//
#include <hip/hip_runtime.h>
#include <hip/hip_cooperative_groups.h>

namespace cg = cooperative_groups;

#define FDIM 1000
#define BDIM 2049
#define NTH  256
#define BT   16
#define NBT  129          // ceil(BDIM/BT)

// ---- fused (cooperative) geometry: 903 blocks, needs 4 blocks/CU (1024 cap) ----
#define CFS   7           // f splits
#define CFT   144         // f per block (16*9), guarded by f < FDIM (7*144=1008)
#define CNII  9           // per-thread point slots (fully unrolled, static idx)
#define CGRID (NBT * CFS) // 903 blocks

// ---- fallback geometry: the proven 3-kernel pipeline ----
#define FFS   8
#define FFT   125
#define FGRID (NBT * FFS)

// out layout (floats): y_out (F,B,C,2,S) | v (F,B,S) | R (B,C,C,2,S)
#define V_OFF 32784000ull
#define R_OFF 40980000ull

// ws layout (floats): part regions sized for stride 8 >= CFS
#define P2_OFF ((size_t)BDIM * 8 * 20)

#define EPSF 1.1920928955078125e-07f
#define REGC 3.4526698300124393e-04f

// ===================== fused cooperative kernel =====================
//   P1: stream y -> v1 (registers), partial R1 -> part1      | grid.sync
//   P2: reduce R1, filter (v1,x) -> v2 (regs), partial R2    | grid.sync
//   P3: reduce R2, write Rout; filter (v2,x) -> y_out, v
__global__ __launch_bounds__(NTH, 4) void k_fused(
    const float* __restrict__ y, const float* __restrict__ x,
    float* __restrict__ yout, float* __restrict__ vout, float* __restrict__ Rout,
    float* __restrict__ part1, float* __restrict__ part2,
    const int* __restrict__ itp)
{
    cg::grid_group gg = cg::this_grid();
    const int btile = blockIdx.x / CFS;
    const int fs    = blockIdx.x % CFS;
    const int tid   = threadIdx.x;
    const int bs    = tid & 15;
    const int fi    = tid >> 4;          // 0..15
    const int wid   = tid >> 6;
    const int b     = btile * BT + bs;
    const bool vb   = (b < BDIM);
    const int iters = itp[0];
    const int f0    = fs * CFT;

    __shared__ float red[4][16][20];
    __shared__ float rsumS[16][20];
    __shared__ float rnormS[16][16];

    // ---------------- Phase 1 ----------------
    float vst[CNII][4];
    float acc[20];
    #pragma unroll
    for (int j = 0; j < 20; ++j) acc[j] = 0.f;

    #pragma unroll
    for (int ii = 0; ii < CNII; ++ii) {
        const int f = f0 + ii * 16 + fi;
        #pragma unroll
        for (int s = 0; s < 4; ++s) vst[ii][s] = 0.f;
        if ((f < FDIM) && vb) {
            const size_t e = (size_t)f * BDIM + b;
            const float4* yp = reinterpret_cast<const float4*>(y) + e * 4;
            const float4 a0 = yp[0], a1 = yp[1], a2 = yp[2], a3 = yp[3];
            const float y0r[4] = {a0.x,a0.y,a0.z,a0.w};
            const float y0i[4] = {a1.x,a1.y,a1.z,a1.w};
            const float y1r[4] = {a2.x,a2.y,a2.z,a2.w};
            const float y1i[4] = {a3.x,a3.y,a3.z,a3.w};
            #pragma unroll
            for (int s = 0; s < 4; ++s) {
                const float p0 = y0r[s]*y0r[s] + y0i[s]*y0i[s];
                const float p1 = y1r[s]*y1r[s] + y1i[s]*y1i[s];
                vst[ii][s] = 0.5f * (p0 + p1);
                acc[s]    += p0;
                acc[4+s]  += p1;
                acc[8+s]  += y0r[s]*y1r[s] + y0i[s]*y1i[s];
                acc[12+s] += y0i[s]*y1r[s] - y0r[s]*y1i[s];
                acc[16+s] += vst[ii][s];
            }
        }
    }
    #pragma unroll
    for (int j = 0; j < 20; ++j) {
        float t = acc[j];
        t += __shfl_xor(t, 16);
        t += __shfl_xor(t, 32);
        acc[j] = t;
    }
    if ((tid & 63) < 16) {
        #pragma unroll
        for (int j = 0; j < 20; ++j) red[wid][bs][j] = acc[j];
    }
    __syncthreads();
    for (int idx = tid; idx < 320; idx += NTH) {
        const int bss = idx & 15, j = idx >> 4;
        const int bb = btile * BT + bss;
        if (bb < BDIM)
            part1[((size_t)bb * CFS + fs) * 20 + j] =
                red[0][bss][j] + red[1][bss][j] + red[2][bss][j] + red[3][bss][j];
    }

    gg.sync();

    // ---------------- Phase 2 ----------------
    for (int idx = tid; idx < 320; idx += NTH) {
        const int bss = idx & 15, j = idx >> 4;
        const int bb = btile * BT + bss;
        float s = 0.f;
        if (bb < BDIM) {
            #pragma unroll
            for (int q = 0; q < CFS; ++q) s += part1[((size_t)bb * CFS + q) * 20 + j];
        }
        rsumS[bss][j] = s;
    }
    __syncthreads();
    {
        const int bss = tid & 15, j = tid >> 4;   // 256 threads == 16x16
        rnormS[bss][j] = rsumS[bss][j] / (EPSF + rsumS[bss][16 + (j & 3)]);
    }
    __syncthreads();

    if (iters >= 2) {
        float rn00[4], rn11[4], rn01r[4], rn01i[4];
        #pragma unroll
        for (int s = 0; s < 4; ++s) {
            rn00[s]=rnormS[bs][s]; rn11[s]=rnormS[bs][4+s];
            rn01r[s]=rnormS[bs][8+s]; rn01i[s]=rnormS[bs][12+s];
        }
        #pragma unroll
        for (int j = 0; j < 20; ++j) acc[j] = 0.f;

        #pragma unroll
        for (int ii = 0; ii < CNII; ++ii) {
            const int f = f0 + ii * 16 + fi;
            if ((f < FDIM) && vb) {
                const size_t e = (size_t)f * BDIM + b;
                const float4 xv = reinterpret_cast<const float4*>(x)[e];
                float c00 = REGC, c11 = REGC, c01r = 0.f, c01i = 0.f;
                #pragma unroll
                for (int s = 0; s < 4; ++s) {
                    c00  += vst[ii][s]*rn00[s];
                    c11  += vst[ii][s]*rn11[s];
                    c01r += vst[ii][s]*rn01r[s];
                    c01i += vst[ii][s]*rn01i[s];
                }
                const float det  = c00*c11 - (c01r*c01r + c01i*c01i);
                const float invd = det / (det*det);
                const float i00 = invd*c11, i11 = invd*c00;
                const float i01r = -invd*c01r, i01i = -invd*c01i;
                const float xr0 = xv.x, xi0 = xv.y, xr1 = xv.z, xi1 = xv.w;
                const float w0r = i00*xr0 + (i01r*xr1 - i01i*xi1);
                const float w0i = i00*xi0 + (i01r*xi1 + i01i*xr1);
                const float w1r = (i01r*xr0 + i01i*xi0) + i11*xr1;
                const float w1i = (i01r*xi0 - i01i*xr0) + i11*xi1;
                #pragma unroll
                for (int s = 0; s < 4; ++s) {
                    const float vs = vst[ii][s];
                    const float y0r = vs*(rn00[s]*w0r + (rn01r[s]*w1r - rn01i[s]*w1i));
                    const float y0i = vs*(rn00[s]*w0i + (rn01r[s]*w1i + rn01i[s]*w1r));
                    const float y1r = vs*((rn01r[s]*w0r + rn01i[s]*w0i) + rn11[s]*w1r);
                    const float y1i = vs*((rn01r[s]*w0i - rn01i[s]*w0r) + rn11[s]*w1i);
                    const float p0 = y0r*y0r + y0i*y0i;
                    const float p1 = y1r*y1r + y1i*y1i;
                    const float v2 = 0.5f*(p0 + p1);
                    vst[ii][s] = v2;
                    acc[s]    += p0;
                    acc[4+s]  += p1;
                    acc[8+s]  += y0r*y1r + y0i*y1i;
                    acc[12+s] += y0i*y1r - y0r*y1i;
                    acc[16+s] += v2;
                }
            }
        }
        #pragma unroll
        for (int j = 0; j < 20; ++j) {
            float t = acc[j];
            t += __shfl_xor(t, 16);
            t += __shfl_xor(t, 32);
            acc[j] = t;
        }
        if ((tid & 63) < 16) {
            #pragma unroll
            for (int j = 0; j < 20; ++j) red[wid][bs][j] = acc[j];
        }
        __syncthreads();
        for (int idx = tid; idx < 320; idx += NTH) {
            const int bss = idx & 15, j = idx >> 4;
            const int bb = btile * BT + bss;
            if (bb < BDIM)
                part2[((size_t)bb * CFS + fs) * 20 + j] =
                    red[0][bss][j] + red[1][bss][j] + red[2][bss][j] + red[3][bss][j];
        }
    } else {
        for (int idx = tid; idx < 320; idx += NTH) {
            const int bss = idx & 15, j = idx >> 4;
            const int bb = btile * BT + bss;
            if (bb < BDIM)
                part2[((size_t)bb * CFS + fs) * 20 + j] = (fs == 0) ? rsumS[bss][j] : 0.f;
        }
    }

    gg.sync();

    // ---------------- Phase 3 ----------------
    for (int idx = tid; idx < 320; idx += NTH) {
        const int bss = idx & 15, j = idx >> 4;
        const int bb = btile * BT + bss;
        float s = 0.f;
        if (bb < BDIM) {
            #pragma unroll
            for (int q = 0; q < CFS; ++q) s += part2[((size_t)bb * CFS + q) * 20 + j];
        }
        rsumS[bss][j] = s;
    }
    __syncthreads();
    {
        const int bss = tid & 15, j = tid >> 4;
        rnormS[bss][j] = rsumS[bss][j] / (EPSF + rsumS[bss][16 + (j & 3)]);
    }
    __syncthreads();

    if (fs == 0) {   // R_out
        for (int idx = tid; idx < 512; idx += NTH) {
            const int bss = idx >> 5, r = idx & 31;
            const int bb = btile * BT + bss;
            if (bb < BDIM) {
                const int c = (r>>4)&1, d = (r>>3)&1, ri = (r>>2)&1, s = r&3;
                const bool raw = (iters == 0);
                float val;
                if (c == d) {
                    val = ri ? 0.f : (raw ? rsumS[bss][(c?4:0)+s] : rnormS[bss][(c?4:0)+s]);
                } else {
                    const float re = raw ? rsumS[bss][8+s]  : rnormS[bss][8+s];
                    const float im = raw ? rsumS[bss][12+s] : rnormS[bss][12+s];
                    val = ri ? (c == 0 ? im : -im) : re;
                }
                Rout[(size_t)bb * 32 + r] = val;
            }
        }
    }

    if (iters == 0) {   // y_out = y, v = v1
        #pragma unroll
        for (int ii = 0; ii < CNII; ++ii) {
            const int f = f0 + ii * 16 + fi;
            if ((f < FDIM) && vb) {
                const size_t e = (size_t)f * BDIM + b;
                const float4* yp = reinterpret_cast<const float4*>(y) + e * 4;
                float4* op = reinterpret_cast<float4*>(yout) + e * 4;
                op[0] = yp[0]; op[1] = yp[1]; op[2] = yp[2]; op[3] = yp[3];
                reinterpret_cast<float4*>(vout)[e] =
                    make_float4(vst[ii][0], vst[ii][1], vst[ii][2], vst[ii][3]);
            }
        }
        return;
    }

    float rn00[4], rn11[4], rn01r[4], rn01i[4];
    #pragma unroll
    for (int s = 0; s < 4; ++s) {
        rn00[s]=rnormS[bs][s]; rn11[s]=rnormS[bs][4+s];
        rn01r[s]=rnormS[bs][8+s]; rn01i[s]=rnormS[bs][12+s];
    }

    #pragma unroll
    for (int ii = 0; ii < CNII; ++ii) {
        const int f = f0 + ii * 16 + fi;
        if ((f < FDIM) && vb) {
            const size_t e = (size_t)f * BDIM + b;
            const float4 xv = reinterpret_cast<const float4*>(x)[e];
            float c00 = REGC, c11 = REGC, c01r = 0.f, c01i = 0.f;
            #pragma unroll
            for (int s = 0; s < 4; ++s) {
                c00  += vst[ii][s]*rn00[s];
                c11  += vst[ii][s]*rn11[s];
                c01r += vst[ii][s]*rn01r[s];
                c01i += vst[ii][s]*rn01i[s];
            }
            const float det  = c00*c11 - (c01r*c01r + c01i*c01i);
            const float invd = det / (det*det);
            const float i00 = invd*c11, i11 = invd*c00;
            const float i01r = -invd*c01r, i01i = -invd*c01i;
            const float xr0 = xv.x, xi0 = xv.y, xr1 = xv.z, xi1 = xv.w;
            const float w0r = i00*xr0 + (i01r*xr1 - i01i*xi1);
            const float w0i = i00*xi0 + (i01r*xi1 + i01i*xr1);
            const float w1r = (i01r*xr0 + i01i*xi0) + i11*xr1;
            const float w1i = (i01r*xi0 - i01i*xr0) + i11*xi1;
            float o0r[4], o0i[4], o1r[4], o1i[4];
            #pragma unroll
            for (int s = 0; s < 4; ++s) {
                const float vs = vst[ii][s];
                o0r[s] = vs*(rn00[s]*w0r + (rn01r[s]*w1r - rn01i[s]*w1i));
                o0i[s] = vs*(rn00[s]*w0i + (rn01r[s]*w1i + rn01i[s]*w1r));
                o1r[s] = vs*((rn01r[s]*w0r + rn01i[s]*w0i) + rn11[s]*w1r);
                o1i[s] = vs*((rn01r[s]*w0i - rn01i[s]*w0r) + rn11[s]*w1i);
            }
            float4* op = reinterpret_cast<float4*>(yout) + e * 4;
            op[0] = make_float4(o0r[0], o0r[1], o0r[2], o0r[3]);
            op[1] = make_float4(o0i[0], o0i[1], o0i[2], o0i[3]);
            op[2] = make_float4(o1r[0], o1r[1], o1r[2], o1r[3]);
            op[3] = make_float4(o1i[0], o1i[1], o1i[2], o1i[3]);
            reinterpret_cast<float4*>(vout)[e] =
                make_float4(vst[ii][0], vst[ii][1], vst[ii][2], vst[ii][3]);
        }
    }
}

// ===================== fallback: proven 3-kernel pipeline =====================
__global__ __launch_bounds__(NTH) void k1_power(
    const float* __restrict__ y, float* __restrict__ v, float* __restrict__ part1)
{
    const int btile = blockIdx.x / FFS;
    const int fs    = blockIdx.x % FFS;
    const int tid   = threadIdx.x;
    const int bs    = tid & 15;
    const int fi    = tid >> 4;
    const int wid   = tid >> 6;
    const int b     = btile * BT + bs;
    const bool vb   = (b < BDIM);

    float acc[20];
    #pragma unroll
    for (int j = 0; j < 20; ++j) acc[j] = 0.f;

    const int f0 = fs * FFT;
    #pragma unroll
    for (int ii = 0; ii < 8; ++ii) {
        const int fo = ii * 16 + fi;
        if (fo < FFT && vb) {
            const int f = f0 + fo;
            const size_t e = (size_t)f * BDIM + b;
            const float4* yp = reinterpret_cast<const float4*>(y) + e * 4;
            float4 a0 = yp[0], a1 = yp[1], a2 = yp[2], a3 = yp[3];
            float y0r[4] = {a0.x,a0.y,a0.z,a0.w};
            float y0i[4] = {a1.x,a1.y,a1.z,a1.w};
            float y1r[4] = {a2.x,a2.y,a2.z,a2.w};
            float y1i[4] = {a3.x,a3.y,a3.z,a3.w};
            float vv[4];
            #pragma unroll
            for (int s = 0; s < 4; ++s) {
                const float p0 = y0r[s]*y0r[s] + y0i[s]*y0i[s];
                const float p1 = y1r[s]*y1r[s] + y1i[s]*y1i[s];
                vv[s] = 0.5f * (p0 + p1);
                acc[s]    += p0;
                acc[4+s]  += p1;
                acc[8+s]  += y0r[s]*y1r[s] + y0i[s]*y1i[s];
                acc[12+s] += y0i[s]*y1r[s] - y0r[s]*y1i[s];
                acc[16+s] += vv[s];
            }
            reinterpret_cast<float4*>(v)[e] = make_float4(vv[0], vv[1], vv[2], vv[3]);
        }
    }
    #pragma unroll
    for (int j = 0; j < 20; ++j) {
        float t = acc[j];
        t += __shfl_xor(t, 16);
        t += __shfl_xor(t, 32);
        acc[j] = t;
    }
    __shared__ float red[4][16][20];
    if ((tid & 63) < 16) {
        #pragma unroll
        for (int j = 0; j < 20; ++j) red[wid][bs][j] = acc[j];
    }
    __syncthreads();
    for (int idx = tid; idx < 320; idx += NTH) {
        const int bss = idx & 15, j = idx >> 4;
        const int bb = btile * BT + bss;
        if (bb < BDIM)
            part1[((size_t)bb * FFS + fs) * 20 + j] =
                red[0][bss][j] + red[1][bss][j] + red[2][bss][j] + red[3][bss][j];
    }
}

__global__ __launch_bounds__(NTH) void k3_em(
    const float* __restrict__ x, float* __restrict__ v,
    const float* __restrict__ part1, float* __restrict__ part2,
    const int* __restrict__ itp)
{
    const int btile = blockIdx.x / FFS;
    const int fs    = blockIdx.x % FFS;
    const int tid   = threadIdx.x;
    const int bs    = tid & 15;
    const int fi    = tid >> 4;
    const int wid   = tid >> 6;
    const int b     = btile * BT + bs;
    const bool vb   = (b < BDIM);
    const int iters = itp[0];

    __shared__ float rsumS[16][20];
    __shared__ float rnormS[16][16];
    for (int idx = tid; idx < 320; idx += NTH) {
        const int bss = idx & 15, j = idx >> 4;
        const int bb = btile * BT + bss;
        float s = 0.f;
        if (bb < BDIM) {
            #pragma unroll
            for (int q = 0; q < FFS; ++q) s += part1[((size_t)bb * FFS + q) * 20 + j];
        }
        rsumS[bss][j] = s;
    }
    __syncthreads();
    {
        const int bss = tid & 15, j = tid >> 4;
        rnormS[bss][j] = rsumS[bss][j] / (EPSF + rsumS[bss][16 + (j & 3)]);
    }
    __syncthreads();

    if (iters <= 1) {
        for (int idx = tid; idx < 320; idx += NTH) {
            const int bss = idx & 15, j = idx >> 4;
            const int bb = btile * BT + bss;
            if (bb < BDIM)
                part2[((size_t)bb * FFS + fs) * 20 + j] = (fs == 0) ? rsumS[bss][j] : 0.f;
        }
        return;
    }

    float rn00[4], rn11[4], rn01r[4], rn01i[4];
    #pragma unroll
    for (int s = 0; s < 4; ++s) {
        rn00[s]=rnormS[bs][s]; rn11[s]=rnormS[bs][4+s];
        rn01r[s]=rnormS[bs][8+s]; rn01i[s]=rnormS[bs][12+s];
    }

    float acc[20];
    #pragma unroll
    for (int j = 0; j < 20; ++j) acc[j] = 0.f;

    const int f0 = fs * FFT;
    #pragma unroll
    for (int ii = 0; ii < 8; ++ii) {
        const int fo = ii * 16 + fi;
        if (fo < FFT && vb) {
            const int f = f0 + fo;
            const size_t e = (size_t)f * BDIM + b;
            float4 vv4 = reinterpret_cast<const float4*>(v)[e];
            float4 xv  = reinterpret_cast<const float4*>(x)[e];
            float v1[4] = {vv4.x, vv4.y, vv4.z, vv4.w};
            float c00 = REGC, c11 = REGC, c01r = 0.f, c01i = 0.f;
            #pragma unroll
            for (int s = 0; s < 4; ++s) {
                c00  += v1[s]*rn00[s];
                c11  += v1[s]*rn11[s];
                c01r += v1[s]*rn01r[s];
                c01i += v1[s]*rn01i[s];
            }
            const float det  = c00*c11 - (c01r*c01r + c01i*c01i);
            const float invd = det / (det*det);
            const float i00 = invd*c11, i11 = invd*c00;
            const float i01r = -invd*c01r, i01i = -invd*c01i;
            const float xr0 = xv.x, xi0 = xv.y, xr1 = xv.z, xi1 = xv.w;
            const float w0r = i00*xr0 + (i01r*xr1 - i01i*xi1);
            const float w0i = i00*xi0 + (i01r*xi1 + i01i*xr1);
            const float w1r = (i01r*xr0 + i01i*xi0) + i11*xr1;
            const float w1i = (i01r*xi0 - i01i*xr0) + i11*xi1;
            float v2[4];
            #pragma unroll
            for (int s = 0; s < 4; ++s) {
                const float vs = v1[s];
                const float y0r = vs*(rn00[s]*w0r + (rn01r[s]*w1r - rn01i[s]*w1i));
                const float y0i = vs*(rn00[s]*w0i + (rn01r[s]*w1i + rn01i[s]*w1r));
                const float y1r = vs*((rn01r[s]*w0r + rn01i[s]*w0i) + rn11[s]*w1r);
                const float y1i = vs*((rn01r[s]*w0i - rn01i[s]*w0r) + rn11[s]*w1i);
                const float p0 = y0r*y0r + y0i*y0i;
                const float p1 = y1r*y1r + y1i*y1i;
                v2[s] = 0.5f*(p0 + p1);
                acc[s]    += p0;
                acc[4+s]  += p1;
                acc[8+s]  += y0r*y1r + y0i*y1i;
                acc[12+s] += y0i*y1r - y0r*y1i;
                acc[16+s] += v2[s];
            }
            reinterpret_cast<float4*>(v)[e] = make_float4(v2[0], v2[1], v2[2], v2[3]);
        }
    }
    #pragma unroll
    for (int j = 0; j < 20; ++j) {
        float t = acc[j];
        t += __shfl_xor(t, 16);
        t += __shfl_xor(t, 32);
        acc[j] = t;
    }
    __shared__ float red[4][16][20];
    if ((tid & 63) < 16) {
        #pragma unroll
        for (int j = 0; j < 20; ++j) red[wid][bs][j] = acc[j];
    }
    __syncthreads();
    for (int idx = tid; idx < 320; idx += NTH) {
        const int bss = idx & 15, j = idx >> 4;
        const int bb = btile * BT + bss;
        if (bb < BDIM)
            part2[((size_t)bb * FFS + fs) * 20 + j] =
                red[0][bss][j] + red[1][bss][j] + red[2][bss][j] + red[3][bss][j];
    }
}

__global__ __launch_bounds__(NTH) void k5_final(
    const float* __restrict__ y, const float* __restrict__ x, const float* __restrict__ v,
    const float* __restrict__ part2, float* __restrict__ yout, float* __restrict__ Rout,
    const int* __restrict__ itp)
{
    const int btile = blockIdx.x / FFS;
    const int fs    = blockIdx.x % FFS;
    const int tid   = threadIdx.x;
    const int bs    = tid & 15;
    const int fi    = tid >> 4;
    const int b     = btile * BT + bs;
    const bool vb   = (b < BDIM);
    const int iters = itp[0];

    __shared__ float rsumS[16][20];
    __shared__ float rnormS[16][16];
    for (int idx = tid; idx < 320; idx += NTH) {
        const int bss = idx & 15, j = idx >> 4;
        const int bb = btile * BT + bss;
        float s = 0.f;
        if (bb < BDIM) {
            #pragma unroll
            for (int q = 0; q < FFS; ++q) s += part2[((size_t)bb * FFS + q) * 20 + j];
        }
        rsumS[bss][j] = s;
    }
    __syncthreads();
    {
        const int bss = tid & 15, j = tid >> 4;
        rnormS[bss][j] = rsumS[bss][j] / (EPSF + rsumS[bss][16 + (j & 3)]);
    }
    __syncthreads();

    if (fs == 0) {
        for (int idx = tid; idx < 512; idx += NTH) {
            const int bss = idx >> 5, r = idx & 31;
            const int bb = btile * BT + bss;
            if (bb < BDIM) {
                const int c = (r>>4)&1, d = (r>>3)&1, ri = (r>>2)&1, s = r&3;
                const bool raw = (iters == 0);
                float val;
                if (c == d) {
                    val = ri ? 0.f : (raw ? rsumS[bss][(c?4:0)+s] : rnormS[bss][(c?4:0)+s]);
                } else {
                    const float re = raw ? rsumS[bss][8+s]  : rnormS[bss][8+s];
                    const float im = raw ? rsumS[bss][12+s] : rnormS[bss][12+s];
                    val = ri ? (c == 0 ? im : -im) : re;
                }
                Rout[(size_t)bb * 32 + r] = val;
            }
        }
    }

    const int f0 = fs * FFT;
    if (iters == 0) {
        #pragma unroll
        for (int ii = 0; ii < 8; ++ii) {
            const int fo = ii * 16 + fi;
            if (fo < FFT && vb) {
                const size_t e = (size_t)(f0 + fo) * BDIM + b;
                const float4* yp = reinterpret_cast<const float4*>(y) + e * 4;
                float4* op = reinterpret_cast<float4*>(yout) + e * 4;
                op[0] = yp[0]; op[1] = yp[1]; op[2] = yp[2]; op[3] = yp[3];
            }
        }
        return;
    }

    float rn00[4], rn11[4], rn01r[4], rn01i[4];
    #pragma unroll
    for (int s = 0; s < 4; ++s) {
        rn00[s]=rnormS[bs][s]; rn11[s]=rnormS[bs][4+s];
        rn01r[s]=rnormS[bs][8+s]; rn01i[s]=rnormS[bs][12+s];
    }

    #pragma unroll
    for (int ii = 0; ii < 8; ++ii) {
        const int fo = ii * 16 + fi;
        if (fo < FFT && vb) {
            const int f = f0 + fo;
            const size_t e = (size_t)f * BDIM + b;
            float4 vv4 = reinterpret_cast<const float4*>(v)[e];
            float4 xv  = reinterpret_cast<const float4*>(x)[e];
            float vcur[4] = {vv4.x, vv4.y, vv4.z, vv4.w};
            float c00 = REGC, c11 = REGC, c01r = 0.f, c01i = 0.f;
            #pragma unroll
            for (int s = 0; s < 4; ++s) {
                c00  += vcur[s]*rn00[s];
                c11  += vcur[s]*rn11[s];
                c01r += vcur[s]*rn01r[s];
                c01i += vcur[s]*rn01i[s];
            }
            const float det  = c00*c11 - (c01r*c01r + c01i*c01i);
            const float invd = det / (det*det);
            const float i00 = invd*c11, i11 = invd*c00;
            const float i01r = -invd*c01r, i01i = -invd*c01i;
            const float xr0 = xv.x, xi0 = xv.y, xr1 = xv.z, xi1 = xv.w;
            const float w0r = i00*xr0 + (i01r*xr1 - i01i*xi1);
            const float w0i = i00*xi0 + (i01r*xi1 + i01i*xr1);
            const float w1r = (i01r*xr0 + i01i*xi0) + i11*xr1;
            const float w1i = (i01r*xi0 - i01i*xr0) + i11*xi1;
            float o0r[4], o0i[4], o1r[4], o1i[4];
            #pragma unroll
            for (int s = 0; s < 4; ++s) {
                const float vs = vcur[s];
                o0r[s] = vs*(rn00[s]*w0r + (rn01r[s]*w1r - rn01i[s]*w1i));
                o0i[s] = vs*(rn00[s]*w0i + (rn01r[s]*w1i + rn01i[s]*w1r));
                o1r[s] = vs*((rn01r[s]*w0r + rn01i[s]*w0i) + rn11[s]*w1r);
                o1i[s] = vs*((rn01r[s]*w0i - rn01i[s]*w0r) + rn11[s]*w1i);
            }
            float4* op = reinterpret_cast<float4*>(yout) + e * 4;
            op[0] = make_float4(o0r[0], o0r[1], o0r[2], o0r[3]);
            op[1] = make_float4(o0i[0], o0i[1], o0i[2], o0i[3]);
            op[2] = make_float4(o1r[0], o1r[1], o1r[2], o1r[3]);
            op[3] = make_float4(o1i[0], o1i[1], o1i[2], o1i[3]);
        }
    }
}

extern "C" void kernel_launch(void* const* d_in, const int* in_sizes, int n_in,
                              void* d_out, int out_size, void* d_ws, size_t ws_size,
                              hipStream_t stream) {
    const float* y   = (const float*)d_in[0];
    const float* x   = (const float*)d_in[1];
    const int*   itp = (const int*)d_in[2];
    float* out   = (float*)d_out;
    float* vreg  = out + V_OFF;
    float* Rreg  = out + R_OFF;
    float* part1 = (float*)d_ws;
    float* part2 = part1 + P2_OFF;

    // ---- capacity pre-check (host-only queries; graph-capture-safe) ----
    bool use_coop = false;
    int dev = 0, coop = 0, ncu = 0, maxb = 0;
    if (hipGetDevice(&dev) == hipSuccess &&
        hipDeviceGetAttribute(&coop, hipDeviceAttributeCooperativeLaunch, dev) == hipSuccess &&
        coop != 0 &&
        hipDeviceGetAttribute(&ncu, hipDeviceAttributeMultiprocessorCount, dev) == hipSuccess &&
        hipOccupancyMaxActiveBlocksPerMultiprocessor(&maxb, (const void*)k_fused, NTH, 0) == hipSuccess &&
        (long long)maxb * (long long)ncu >= (long long)CGRID)
        use_coop = true;

    if (use_coop) {
        void* args[] = {(void*)&y, (void*)&x, (void*)&out, (void*)&vreg, (void*)&Rreg,
                        (void*)&part1, (void*)&part2, (void*)&itp};
        if (hipLaunchCooperativeKernel((void*)k_fused, dim3(CGRID), dim3(NTH),
                                       args, 0, stream) != hipSuccess)
            use_coop = false;
    }
    if (!use_coop) {
        k1_power<<<FGRID, NTH, 0, stream>>>(y, vreg, part1);
        k3_em   <<<FGRID, NTH, 0, stream>>>(x, vreg, part1, part2, itp);
        k5_final<<<FGRID, NTH, 0, stream>>>(y, x, vreg, part2, out, Rreg, itp);
    }
}

// Round 4
// 324.149 us; speedup vs baseline: 1.0383x; 1.0360x over previous
//
#include <hip/hip_runtime.h>

#define FDIM 1000
#define BDIM 2049
#define NTH  256
#define FS   8           // f splits
#define FT   125         // f per block (FS*FT == FDIM)
#define BT   16          // b per block
#define NBT  129         // ceil(BDIM/BT)
#define GRID (NBT * FS)

// out layout (floats): y_out (F,B,C,2,S) | v (F,B,S) | R (B,C,C,2,S)
#define V_OFF 32784000ull
#define R_OFF 40980000ull

// ws layout (floats): part1[B][FS][20] | part2[B][FS][20]
#define P2_OFF ((size_t)BDIM * FS * 20)

#define EPSF 1.1920928955078125e-07f
#define REGC 3.4526698300124393e-04f

__device__ __forceinline__ float4 shflx4(float4 v, int m) {
    float4 r;
    r.x = __shfl_xor(v.x, m);
    r.y = __shfl_xor(v.y, m);
    r.z = __shfl_xor(v.z, m);
    r.w = __shfl_xor(v.w, m);
    return r;
}

// 4x4 float4 transpose across lane group {p, p+16, p+32, p+48} (involution).
// Pre:  lane (c,p) holds reg[k] = M[c][k].  Post: reg[k] = M[k][c].
__device__ __forceinline__ void xpose4(float4& r0, float4& r1, float4& r2, float4& r3,
                                       int lane) {
    const bool c0 = (lane & 16) != 0;
    const bool c1 = (lane & 32) != 0;
    {   // swap bit0(k) <-> bit0(c), pairs (r0,r1) and (r2,r3)
        float4 a  = c0 ? r0 : r1;
        float4 bb = shflx4(a, 16);
        if (c0) r0 = bb; else r1 = bb;
        float4 a2 = c0 ? r2 : r3;
        float4 b2 = shflx4(a2, 16);
        if (c0) r2 = b2; else r3 = b2;
    }
    {   // swap bit1(k) <-> bit1(c), pairs (r0,r2) and (r1,r3)
        float4 a  = c1 ? r0 : r2;
        float4 bb = shflx4(a, 32);
        if (c1) r0 = bb; else r2 = bb;
        float4 a2 = c1 ? r1 : r3;
        float4 b2 = shflx4(a2, 32);
        if (c1) r1 = b2; else r3 = b2;
    }
}

// ---------------- K1: stream y (dense loads + transpose) -> v1, partial R1 ----------------
__global__ __launch_bounds__(NTH) void k1_power(
    const float* __restrict__ y, float* __restrict__ v, float* __restrict__ part1)
{
    const int btile = blockIdx.x / FS;
    const int fs    = blockIdx.x % FS;
    const int tid   = threadIdx.x;
    const int lane  = tid & 63;
    const int p     = lane & 15;       // b offset within tile (== old bs)
    const int cq    = lane >> 4;       // 0..3: quarter slot on load, row-in-group as owner
    const int w     = tid >> 6;        // wave id (== old wid)
    const int b     = btile * BT + p;
    const bool vb   = (b < BDIM);
    const int f0    = fs * FT;

    const float4* __restrict__ y4 = reinterpret_cast<const float4*>(y);
    float4* __restrict__ v4 = reinterpret_cast<float4*>(v);

    float acc[20];
    #pragma unroll
    for (int j = 0; j < 20; ++j) acc[j] = 0.f;

    #pragma unroll
    for (int ii = 0; ii < 8; ++ii) {
        const int fob = ii * 16 + 4 * w;   // base row of this wave-iteration
        float4 q0 = make_float4(0.f,0.f,0.f,0.f), q1 = q0, q2 = q0, q3 = q0;
        if (vb) {
            // dense: instr k covers row fob+k's 1 KB; lane (cq,p) takes float4 #(p*4+cq)
            if (fob + 0 < FT) q0 = y4[((size_t)(f0+fob+0)*BDIM + b)*4 + cq];
            if (fob + 1 < FT) q1 = y4[((size_t)(f0+fob+1)*BDIM + b)*4 + cq];
            if (fob + 2 < FT) q2 = y4[((size_t)(f0+fob+2)*BDIM + b)*4 + cq];
            if (fob + 3 < FT) q3 = y4[((size_t)(f0+fob+3)*BDIM + b)*4 + cq];
        }
        xpose4(q0, q1, q2, q3, lane);
        // now: qk = quarter k of point (row fob+cq, b)
        const int fo = fob + cq;           // == old fi-based fo
        if (fo < FT && vb) {
            const size_t e = (size_t)(f0 + fo) * BDIM + b;
            const float y0r[4] = {q0.x,q0.y,q0.z,q0.w};
            const float y0i[4] = {q1.x,q1.y,q1.z,q1.w};
            const float y1r[4] = {q2.x,q2.y,q2.z,q2.w};
            const float y1i[4] = {q3.x,q3.y,q3.z,q3.w};
            float vv[4];
            #pragma unroll
            for (int s = 0; s < 4; ++s) {
                const float p0 = y0r[s]*y0r[s] + y0i[s]*y0i[s];
                const float p1 = y1r[s]*y1r[s] + y1i[s]*y1i[s];
                vv[s] = 0.5f * (p0 + p1);
                acc[s]    += p0;
                acc[4+s]  += p1;
                acc[8+s]  += y0r[s]*y1r[s] + y0i[s]*y1i[s];
                acc[12+s] += y0i[s]*y1r[s] - y0r[s]*y1i[s];
                acc[16+s] += vv[s];
            }
            v4[e] = make_float4(vv[0], vv[1], vv[2], vv[3]);
        }
    }
    #pragma unroll
    for (int j = 0; j < 20; ++j) {
        float t = acc[j];
        t += __shfl_xor(t, 16);
        t += __shfl_xor(t, 32);
        acc[j] = t;
    }
    __shared__ float red[4][16][20];
    if ((tid & 63) < 16) {
        #pragma unroll
        for (int j = 0; j < 20; ++j) red[w][p][j] = acc[j];
    }
    __syncthreads();
    for (int idx = tid; idx < 320; idx += NTH) {
        const int bss = idx & 15, j = idx >> 4;
        const int bb = btile * BT + bss;
        if (bb < BDIM)
            part1[((size_t)bb * FS + fs) * 20 + j] =
                red[0][bss][j] + red[1][bss][j] + red[2][bss][j] + red[3][bss][j];
    }
}

// ---------------- K3: v1,x -> yc1 (on the fly) -> v2, partial R2 (dense already) ----------------
__global__ __launch_bounds__(NTH) void k3_em(
    const float* __restrict__ x, float* __restrict__ v,
    const float* __restrict__ part1, float* __restrict__ part2,
    const int* __restrict__ itp)
{
    const int btile = blockIdx.x / FS;
    const int fs    = blockIdx.x % FS;
    const int tid   = threadIdx.x;
    const int bs    = tid & 15;
    const int fi    = tid >> 4;
    const int wid   = tid >> 6;
    const int b     = btile * BT + bs;
    const bool vb   = (b < BDIM);
    const int iters = itp[0];

    __shared__ float rsumS[16][20];
    __shared__ float rnormS[16][16];
    for (int idx = tid; idx < 320; idx += NTH) {
        const int bss = idx & 15, j = idx >> 4;
        const int bb = btile * BT + bss;
        float s = 0.f;
        if (bb < BDIM) {
            #pragma unroll
            for (int q = 0; q < FS; ++q) s += part1[((size_t)bb * FS + q) * 20 + j];
        }
        rsumS[bss][j] = s;
    }
    __syncthreads();
    {
        const int bss = tid & 15, j = tid >> 4;
        rnormS[bss][j] = rsumS[bss][j] / (EPSF + rsumS[bss][16 + (j & 3)]);
    }
    __syncthreads();

    if (iters <= 1) {   // pass-through: R stays R1, v stays v1
        for (int idx = tid; idx < 320; idx += NTH) {
            const int bss = idx & 15, j = idx >> 4;
            const int bb = btile * BT + bss;
            if (bb < BDIM)
                part2[((size_t)bb * FS + fs) * 20 + j] = (fs == 0) ? rsumS[bss][j] : 0.f;
        }
        return;
    }

    float rn00[4], rn11[4], rn01r[4], rn01i[4];
    #pragma unroll
    for (int s = 0; s < 4; ++s) {
        rn00[s]=rnormS[bs][s]; rn11[s]=rnormS[bs][4+s];
        rn01r[s]=rnormS[bs][8+s]; rn01i[s]=rnormS[bs][12+s];
    }

    float acc[20];
    #pragma unroll
    for (int j = 0; j < 20; ++j) acc[j] = 0.f;

    const int f0 = fs * FT;
    #pragma unroll
    for (int ii = 0; ii < 8; ++ii) {
        const int fo = ii * 16 + fi;
        if (fo < FT && vb) {
            const int f = f0 + fo;
            const size_t e = (size_t)f * BDIM + b;
            float4 vv4 = reinterpret_cast<const float4*>(v)[e];
            float4 xv  = reinterpret_cast<const float4*>(x)[e];
            float v1[4] = {vv4.x, vv4.y, vv4.z, vv4.w};
            float c00 = REGC, c11 = REGC, c01r = 0.f, c01i = 0.f;
            #pragma unroll
            for (int s = 0; s < 4; ++s) {
                c00  += v1[s]*rn00[s];
                c11  += v1[s]*rn11[s];
                c01r += v1[s]*rn01r[s];
                c01i += v1[s]*rn01i[s];
            }
            const float det  = c00*c11 - (c01r*c01r + c01i*c01i);
            const float invd = det / (det*det);
            const float i00 = invd*c11, i11 = invd*c00;
            const float i01r = -invd*c01r, i01i = -invd*c01i;
            const float xr0 = xv.x, xi0 = xv.y, xr1 = xv.z, xi1 = xv.w;
            const float w0r = i00*xr0 + (i01r*xr1 - i01i*xi1);
            const float w0i = i00*xi0 + (i01r*xi1 + i01i*xr1);
            const float w1r = (i01r*xr0 + i01i*xi0) + i11*xr1;
            const float w1i = (i01r*xi0 - i01i*xr0) + i11*xi1;
            float v2[4];
            #pragma unroll
            for (int s = 0; s < 4; ++s) {
                const float vs = v1[s];
                const float y0r = vs*(rn00[s]*w0r + (rn01r[s]*w1r - rn01i[s]*w1i));
                const float y0i = vs*(rn00[s]*w0i + (rn01r[s]*w1i + rn01i[s]*w1r));
                const float y1r = vs*((rn01r[s]*w0r + rn01i[s]*w0i) + rn11[s]*w1r);
                const float y1i = vs*((rn01r[s]*w0i - rn01i[s]*w0r) + rn11[s]*w1i);
                const float p0 = y0r*y0r + y0i*y0i;
                const float p1 = y1r*y1r + y1i*y1i;
                v2[s] = 0.5f*(p0 + p1);
                acc[s]    += p0;
                acc[4+s]  += p1;
                acc[8+s]  += y0r*y1r + y0i*y1i;
                acc[12+s] += y0i*y1r - y0r*y1i;
                acc[16+s] += v2[s];
            }
            reinterpret_cast<float4*>(v)[e] = make_float4(v2[0], v2[1], v2[2], v2[3]);
        }
    }
    #pragma unroll
    for (int j = 0; j < 20; ++j) {
        float t = acc[j];
        t += __shfl_xor(t, 16);
        t += __shfl_xor(t, 32);
        acc[j] = t;
    }
    __shared__ float red[4][16][20];
    if ((tid & 63) < 16) {
        #pragma unroll
        for (int j = 0; j < 20; ++j) red[wid][bs][j] = acc[j];
    }
    __syncthreads();
    for (int idx = tid; idx < 320; idx += NTH) {
        const int bss = idx & 15, j = idx >> 4;
        const int bb = btile * BT + bss;
        if (bb < BDIM)
            part2[((size_t)bb * FS + fs) * 20 + j] =
                red[0][bss][j] + red[1][bss][j] + red[2][bss][j] + red[3][bss][j];
    }
}

// ---------------- K5: v2,x -> yc2 -> y_out (transpose + dense stores); R_out ----------------
__global__ __launch_bounds__(NTH) void k5_final(
    const float* __restrict__ y, const float* __restrict__ x, const float* __restrict__ v,
    const float* __restrict__ part2, float* __restrict__ yout, float* __restrict__ Rout,
    const int* __restrict__ itp)
{
    const int btile = blockIdx.x / FS;
    const int fs    = blockIdx.x % FS;
    const int tid   = threadIdx.x;
    const int lane  = tid & 63;
    const int p     = lane & 15;
    const int cq    = lane >> 4;
    const int w     = tid >> 6;
    const int b     = btile * BT + p;
    const bool vb   = (b < BDIM);
    const int iters = itp[0];
    const int f0    = fs * FT;

    __shared__ float rsumS[16][20];
    __shared__ float rnormS[16][16];
    for (int idx = tid; idx < 320; idx += NTH) {
        const int bss = idx & 15, j = idx >> 4;
        const int bb = btile * BT + bss;
        float s = 0.f;
        if (bb < BDIM) {
            #pragma unroll
            for (int q = 0; q < FS; ++q) s += part2[((size_t)bb * FS + q) * 20 + j];
        }
        rsumS[bss][j] = s;
    }
    __syncthreads();
    {
        const int bss = tid & 15, j = tid >> 4;
        rnormS[bss][j] = rsumS[bss][j] / (EPSF + rsumS[bss][16 + (j & 3)]);
    }
    __syncthreads();

    if (fs == 0) {   // R_out
        for (int idx = tid; idx < 512; idx += NTH) {
            const int bss = idx >> 5, r = idx & 31;
            const int bb = btile * BT + bss;
            if (bb < BDIM) {
                const int c = (r>>4)&1, d = (r>>3)&1, ri = (r>>2)&1, s = r&3;
                const bool raw = (iters == 0);
                float val;
                if (c == d) {
                    val = ri ? 0.f : (raw ? rsumS[bss][(c?4:0)+s] : rnormS[bss][(c?4:0)+s]);
                } else {
                    const float re = raw ? rsumS[bss][8+s]  : rnormS[bss][8+s];
                    const float im = raw ? rsumS[bss][12+s] : rnormS[bss][12+s];
                    val = ri ? (c == 0 ? im : -im) : re;
                }
                Rout[(size_t)bb * 32 + r] = val;
            }
        }
    }

    const float4* __restrict__ y4 = reinterpret_cast<const float4*>(y);
    const float4* __restrict__ v4 = reinterpret_cast<const float4*>(v);
    const float4* __restrict__ x4 = reinterpret_cast<const float4*>(x);
    float4* __restrict__ o4 = reinterpret_cast<float4*>(yout);

    if (iters == 0) {   // y_out = y: dense row copy, no transpose needed
        #pragma unroll
        for (int ii = 0; ii < 8; ++ii) {
            const int fob = ii * 16 + 4 * w;
            if (vb) {
                if (fob + 0 < FT) { const size_t i0 = ((size_t)(f0+fob+0)*BDIM + b)*4 + cq; o4[i0] = y4[i0]; }
                if (fob + 1 < FT) { const size_t i1 = ((size_t)(f0+fob+1)*BDIM + b)*4 + cq; o4[i1] = y4[i1]; }
                if (fob + 2 < FT) { const size_t i2 = ((size_t)(f0+fob+2)*BDIM + b)*4 + cq; o4[i2] = y4[i2]; }
                if (fob + 3 < FT) { const size_t i3 = ((size_t)(f0+fob+3)*BDIM + b)*4 + cq; o4[i3] = y4[i3]; }
            }
        }
        return;
    }

    float rn00[4], rn11[4], rn01r[4], rn01i[4];
    #pragma unroll
    for (int s = 0; s < 4; ++s) {
        rn00[s]=rnormS[p][s]; rn11[s]=rnormS[p][4+s];
        rn01r[s]=rnormS[p][8+s]; rn01i[s]=rnormS[p][12+s];
    }

    #pragma unroll
    for (int ii = 0; ii < 8; ++ii) {
        const int fob = ii * 16 + 4 * w;
        const int fo  = fob + cq;
        float4 q0 = make_float4(0.f,0.f,0.f,0.f), q1 = q0, q2 = q0, q3 = q0;
        if (fo < FT && vb) {
            const size_t e = (size_t)(f0 + fo) * BDIM + b;
            float4 vv4 = v4[e];
            float4 xv  = x4[e];
            float vcur[4] = {vv4.x, vv4.y, vv4.z, vv4.w};
            float c00 = REGC, c11 = REGC, c01r = 0.f, c01i = 0.f;
            #pragma unroll
            for (int s = 0; s < 4; ++s) {
                c00  += vcur[s]*rn00[s];
                c11  += vcur[s]*rn11[s];
                c01r += vcur[s]*rn01r[s];
                c01i += vcur[s]*rn01i[s];
            }
            const float det  = c00*c11 - (c01r*c01r + c01i*c01i);
            const float invd = det / (det*det);
            const float i00 = invd*c11, i11 = invd*c00;
            const float i01r = -invd*c01r, i01i = -invd*c01i;
            const float xr0 = xv.x, xi0 = xv.y, xr1 = xv.z, xi1 = xv.w;
            const float w0r = i00*xr0 + (i01r*xr1 - i01i*xi1);
            const float w0i = i00*xi0 + (i01r*xi1 + i01i*xr1);
            const float w1r = (i01r*xr0 + i01i*xi0) + i11*xr1;
            const float w1i = (i01r*xi0 - i01i*xr0) + i11*xi1;
            float o0r[4], o0i[4], o1r[4], o1i[4];
            #pragma unroll
            for (int s = 0; s < 4; ++s) {
                const float vs = vcur[s];
                o0r[s] = vs*(rn00[s]*w0r + (rn01r[s]*w1r - rn01i[s]*w1i));
                o0i[s] = vs*(rn00[s]*w0i + (rn01r[s]*w1i + rn01i[s]*w1r));
                o1r[s] = vs*((rn01r[s]*w0r + rn01i[s]*w0i) + rn11[s]*w1r);
                o1i[s] = vs*((rn01r[s]*w0i - rn01i[s]*w0r) + rn11[s]*w1i);
            }
            q0 = make_float4(o0r[0], o0r[1], o0r[2], o0r[3]);
            q1 = make_float4(o0i[0], o0i[1], o0i[2], o0i[3]);
            q2 = make_float4(o1r[0], o1r[1], o1r[2], o1r[3]);
            q3 = make_float4(o1i[0], o1i[1], o1i[2], o1i[3]);
        }
        // owner-major -> store-major (same involution), then dense row stores
        xpose4(q0, q1, q2, q3, lane);
        if (vb) {
            if (fob + 0 < FT) o4[((size_t)(f0+fob+0)*BDIM + b)*4 + cq] = q0;
            if (fob + 1 < FT) o4[((size_t)(f0+fob+1)*BDIM + b)*4 + cq] = q1;
            if (fob + 2 < FT) o4[((size_t)(f0+fob+2)*BDIM + b)*4 + cq] = q2;
            if (fob + 3 < FT) o4[((size_t)(f0+fob+3)*BDIM + b)*4 + cq] = q3;
        }
    }
}

extern "C" void kernel_launch(void* const* d_in, const int* in_sizes, int n_in,
                              void* d_out, int out_size, void* d_ws, size_t ws_size,
                              hipStream_t stream) {
    const float* y   = (const float*)d_in[0];
    const float* x   = (const float*)d_in[1];
    const int*   itp = (const int*)d_in[2];
    float* out   = (float*)d_out;
    float* vreg  = out + V_OFF;
    float* Rreg  = out + R_OFF;
    float* part1 = (float*)d_ws;
    float* part2 = part1 + P2_OFF;

    k1_power<<<GRID, NTH, 0, stream>>>(y, vreg, part1);
    k3_em   <<<GRID, NTH, 0, stream>>>(x, vreg, part1, part2, itp);
    k5_final<<<GRID, NTH, 0, stream>>>(y, x, vreg, part2, out, Rreg, itp);
}